// Round 1
// baseline (76.659 us; speedup 1.0000x reference)
//
#include <hip/hip_runtime.h>
#include <hip/hip_bf16.h>

#define NROW 4096      // 2B
#define HALFB 2048     // B
#define CDIM 1024
#define INV_T 2.0f     // 1/0.5

typedef __attribute__((ext_vector_type(8))) short bf16x8;
typedef __attribute__((ext_vector_type(4))) float f32x4;

__device__ __forceinline__ float bf2f(unsigned short u) {
    union { unsigned int u; float f; } c; c.u = ((unsigned int)u) << 16; return c.f;
}
__device__ __forceinline__ unsigned short f2bf(float f) {
    __hip_bfloat16 h = __float2bfloat16(f);
    union { __hip_bfloat16 h; unsigned short u; } c; c.h = h; return c.u;
}

// ---------------- Kernel 1: row L2-normalize + bf16 pack ----------------
// grid = NROW blocks x 256 threads; each thread handles 4 floats (float4)
__global__ __launch_bounds__(256) void normalize_kernel(
        const float* __restrict__ z1, const float* __restrict__ z2,
        unsigned short* __restrict__ zb) {
    const int row = blockIdx.x;
    const int t = threadIdx.x;
    const float* src = (row < HALFB) ? (z1 + (size_t)row * CDIM)
                                     : (z2 + (size_t)(row - HALFB) * CDIM);
    float4 v = ((const float4*)src)[t];
    float ss = v.x * v.x + v.y * v.y + v.z * v.z + v.w * v.w;
    #pragma unroll
    for (int off = 1; off < 64; off <<= 1) ss += __shfl_xor(ss, off);
    __shared__ float wsum[4];
    const int lane = t & 63, wv = t >> 6;
    if (lane == 0) wsum[wv] = ss;
    __syncthreads();
    const float tot = wsum[0] + wsum[1] + wsum[2] + wsum[3];
    const float scale = 1.0f / fmaxf(sqrtf(tot), 1e-12f);
    ushort4 p;
    p.x = f2bf(v.x * scale);
    p.y = f2bf(v.y * scale);
    p.z = f2bf(v.z * scale);
    p.w = f2bf(v.w * scale);
    ((ushort4*)(zb + (size_t)row * CDIM))[t] = p;
}

// ---------------- Kernel 2: fused GEMM (z zb^T) + exp + row-sum ----------------
// grid = (32,32), 256 threads (4 waves, 2x2), tile 128x128, BK=64
__global__ __launch_bounds__(256) void gemm_den_kernel(
        const unsigned short* __restrict__ zb, float* __restrict__ den) {
    __shared__ __align__(16) unsigned short As[128 * 64];
    __shared__ __align__(16) unsigned short Bs[128 * 64];
    const int i0 = blockIdx.x * 128;
    const int j0 = blockIdx.y * 128;
    const int tid = threadIdx.x;
    const int wave = tid >> 6, lane = tid & 63;
    const int wr = wave >> 1, wc = wave & 1;

    f32x4 acc[4][4];
    #pragma unroll
    for (int m = 0; m < 4; m++)
        #pragma unroll
        for (int n = 0; n < 4; n++) acc[m][n] = (f32x4){0.f, 0.f, 0.f, 0.f};

    // staging geometry: each 1024B LDS chunk = 8 rows of 64 bf16 (128B/row)
    const int crow = lane >> 3;        // row within chunk
    const int ccol = (lane & 7) * 8;   // bf16 col offset (16B per lane)

    for (int k0 = 0; k0 < CDIM; k0 += 64) {
        #pragma unroll
        for (int c = 0; c < 4; ++c) {
            const int chunk = wave * 4 + c;   // wave-uniform
            const unsigned short* ga =
                zb + (size_t)(i0 + chunk * 8 + crow) * CDIM + (k0 + ccol);
            const unsigned short* gb =
                zb + (size_t)(j0 + chunk * 8 + crow) * CDIM + (k0 + ccol);
            __builtin_amdgcn_global_load_lds(
                (const __attribute__((address_space(1))) void*)ga,
                (__attribute__((address_space(3))) void*)((char*)As + chunk * 1024),
                16, 0, 0);
            __builtin_amdgcn_global_load_lds(
                (const __attribute__((address_space(1))) void*)gb,
                (__attribute__((address_space(3))) void*)((char*)Bs + chunk * 1024),
                16, 0, 0);
        }
        __syncthreads();
        #pragma unroll
        for (int kk = 0; kk < 64; kk += 32) {
            bf16x8 a[4], b[4];
            #pragma unroll
            for (int m = 0; m < 4; m++) {
                const int row = wr * 64 + m * 16 + (lane & 15);
                a[m] = *(const bf16x8*)(As + row * 64 + kk + (lane >> 4) * 8);
            }
            #pragma unroll
            for (int n = 0; n < 4; n++) {
                const int row = wc * 64 + n * 16 + (lane & 15);
                b[n] = *(const bf16x8*)(Bs + row * 64 + kk + (lane >> 4) * 8);
            }
            #pragma unroll
            for (int m = 0; m < 4; m++)
                #pragma unroll
                for (int n = 0; n < 4; n++)
                    acc[m][n] = __builtin_amdgcn_mfma_f32_16x16x32_bf16(
                        a[m], b[n], acc[m][n], 0, 0, 0);
        }
        __syncthreads();
    }

    // epilogue: exp(2*s), reduce across the 16 lanes holding one row's cols,
    // one atomicAdd per (row, wave)
    #pragma unroll
    for (int m = 0; m < 4; m++) {
        #pragma unroll
        for (int r = 0; r < 4; r++) {
            float rs = 0.f;
            #pragma unroll
            for (int n = 0; n < 4; n++) rs += __expf(INV_T * acc[m][n][r]);
            rs += __shfl_xor(rs, 1);
            rs += __shfl_xor(rs, 2);
            rs += __shfl_xor(rs, 4);
            rs += __shfl_xor(rs, 8);
            if ((lane & 15) == 0) {
                const int grow = i0 + wr * 64 + m * 16 + (lane >> 4) * 4 + r;
                atomicAdd(&den[grow], rs);
            }
        }
    }
}

// ---------------- Kernel 3: positives pos[i] = dot(zb[i], zb[(i+B)%2B]) ----------------
// 4 waves/block, one row per wave
__global__ __launch_bounds__(256) void pos_kernel(
        const unsigned short* __restrict__ zb, float* __restrict__ pos) {
    const int wave = threadIdx.x >> 6, lane = threadIdx.x & 63;
    const int i = blockIdx.x * 4 + wave;
    const int p = (i + HALFB) & (NROW - 1);
    const unsigned short* a = zb + (size_t)i * CDIM;
    const unsigned short* b = zb + (size_t)p * CDIM;
    float s = 0.f;
    #pragma unroll
    for (int it = 0; it < 2; ++it) {
        const int base = it * 512 + lane * 8;
        bf16x8 va = *(const bf16x8*)(a + base);
        bf16x8 vb = *(const bf16x8*)(b + base);
        #pragma unroll
        for (int j = 0; j < 8; ++j)
            s += bf2f((unsigned short)va[j]) * bf2f((unsigned short)vb[j]);
    }
    #pragma unroll
    for (int off = 1; off < 64; off <<= 1) s += __shfl_xor(s, off);
    if (lane == 0) pos[i] = s;
}

// ---------------- Kernel 4: final loss ----------------
__global__ __launch_bounds__(256) void loss_kernel(
        const float* __restrict__ den, const float* __restrict__ pos,
        float* __restrict__ out) {
    const float E2 = 7.3890560989306495f;  // exp(2) = diagonal term
    const int tid = threadIdx.x;
    float acc = 0.f;
    for (int i = tid; i < NROW; i += 256)
        acc += INV_T * pos[i] - logf(den[i] - E2);
    #pragma unroll
    for (int off = 1; off < 64; off <<= 1) acc += __shfl_xor(acc, off);
    __shared__ float wsum[4];
    const int lane = tid & 63, wv = tid >> 6;
    if (lane == 0) wsum[wv] = acc;
    __syncthreads();
    if (tid == 0) out[0] = -(wsum[0] + wsum[1] + wsum[2] + wsum[3]) * (1.0f / NROW);
}

extern "C" void kernel_launch(void* const* d_in, const int* in_sizes, int n_in,
                              void* d_out, int out_size, void* d_ws, size_t ws_size,
                              hipStream_t stream) {
    const float* z1 = (const float*)d_in[0];
    const float* z2 = (const float*)d_in[1];
    float* out = (float*)d_out;

    // workspace layout
    unsigned short* zb = (unsigned short*)d_ws;                      // 8 MB
    float* den = (float*)((char*)d_ws + (size_t)NROW * CDIM * 2);    // 16 KB
    float* pos = den + NROW;                                         // 16 KB

    normalize_kernel<<<NROW, 256, 0, stream>>>(z1, z2, zb);
    hipMemsetAsync(den, 0, NROW * sizeof(float), stream);
    dim3 grid(NROW / 128, NROW / 128);
    gemm_den_kernel<<<grid, 256, 0, stream>>>(zb, den);
    pos_kernel<<<NROW / 4, 256, 0, stream>>>(zb, pos);
    loss_kernel<<<1, 256, 0, stream>>>(den, pos, out);
}

// Round 2
// 54.022 us; speedup vs baseline: 1.4190x; 1.4190x over previous
//
#include <hip/hip_runtime.h>
#include <hip/hip_bf16.h>

#define NROW 4096      // 2B
#define HALFB 2048     // B
#define CDIM 1024
#define INV_T 2.0f     // 1/0.5
#define NBLK 32        // NROW / 128
#define NTRI 528       // NBLK*(NBLK+1)/2

typedef __attribute__((ext_vector_type(8))) short bf16x8;
typedef __attribute__((ext_vector_type(4))) float f32x4;

__device__ __forceinline__ float bf2f(unsigned short u) {
    union { unsigned int u; float f; } c; c.u = ((unsigned int)u) << 16; return c.f;
}
__device__ __forceinline__ unsigned short f2bf(float f) {
    __hip_bfloat16 h = __float2bfloat16(f);
    union { __hip_bfloat16 h; unsigned short u; } c; c.h = h; return c.u;
}

// ---------------- Kernel 1: row L2-normalize + bf16 pack ----------------
__global__ __launch_bounds__(256) void normalize_kernel(
        const float* __restrict__ z1, const float* __restrict__ z2,
        unsigned short* __restrict__ zb) {
    const int row = blockIdx.x;
    const int t = threadIdx.x;
    const float* src = (row < HALFB) ? (z1 + (size_t)row * CDIM)
                                     : (z2 + (size_t)(row - HALFB) * CDIM);
    float4 v = ((const float4*)src)[t];
    float ss = v.x * v.x + v.y * v.y + v.z * v.z + v.w * v.w;
    #pragma unroll
    for (int off = 1; off < 64; off <<= 1) ss += __shfl_xor(ss, off);
    __shared__ float wsum[4];
    const int lane = t & 63, wv = t >> 6;
    if (lane == 0) wsum[wv] = ss;
    __syncthreads();
    const float tot = wsum[0] + wsum[1] + wsum[2] + wsum[3];
    const float scale = 1.0f / fmaxf(sqrtf(tot), 1e-12f);
    ushort4 p;
    p.x = f2bf(v.x * scale);
    p.y = f2bf(v.y * scale);
    p.z = f2bf(v.z * scale);
    p.w = f2bf(v.w * scale);
    ((ushort4*)(zb + (size_t)row * CDIM))[t] = p;
}

// ---------------- Kernel 2: upper-triangle GEMM + exp + row/col sums ----------------
// grid = NTRI (528) blocks, 256 threads (4 waves, 2x2), tile 128x128, BK=64
// Symmetry: block (bi,bj), bi<bj contributes row-sums to den[i-panel] and
// col-sums to den[j-panel]. Diagonal blocks: row-sums only, single staging.
// LDS swizzle (T2, rule 21): linear LDS dest for global_load_lds, source col
// pre-swizzled by ^(row&7), read col swizzled by the same involution.
__global__ __launch_bounds__(256) void gemm_den_kernel(
        const unsigned short* __restrict__ zb, float* __restrict__ den) {
    __shared__ __align__(16) unsigned short As[128 * 64];
    __shared__ __align__(16) unsigned short Bs[128 * 64];

    // XCD-aware swizzle (528 % 8 == 0 -> bijective), then triangle decode
    const int orig = blockIdx.x;
    int swz = (orig & 7) * (NTRI / 8) + (orig >> 3);
    int bi = 0, rem = swz;
    while (rem >= NBLK - bi) { rem -= NBLK - bi; ++bi; }
    const int bj = bi + rem;
    const int i0 = bi * 128, j0 = bj * 128;
    const bool diag = (bi == bj);

    const int tid = threadIdx.x;
    const int wave = tid >> 6, lane = tid & 63;
    const int wr = wave >> 1, wc = wave & 1;

    f32x4 acc[4][4];
    #pragma unroll
    for (int m = 0; m < 4; m++)
        #pragma unroll
        for (int n = 0; n < 4; n++) acc[m][n] = (f32x4){0.f, 0.f, 0.f, 0.f};

    // staging geometry: each 1024B LDS chunk = 8 rows of 64 bf16 (128B/row)
    const int crow = lane >> 3;                      // row within chunk (0..7)
    const int ccol = ((lane & 7) ^ crow) * 8;        // SWIZZLED source col (elems)

    for (int k0 = 0; k0 < CDIM; k0 += 64) {
        #pragma unroll
        for (int c = 0; c < 4; ++c) {
            const int chunk = wave * 4 + c;          // wave-uniform
            const unsigned short* ga =
                zb + (size_t)(i0 + chunk * 8 + crow) * CDIM + (k0 + ccol);
            __builtin_amdgcn_global_load_lds(
                (const __attribute__((address_space(1))) void*)ga,
                (__attribute__((address_space(3))) void*)((char*)As + chunk * 1024),
                16, 0, 0);
            if (!diag) {
                const unsigned short* gb =
                    zb + (size_t)(j0 + chunk * 8 + crow) * CDIM + (k0 + ccol);
                __builtin_amdgcn_global_load_lds(
                    (const __attribute__((address_space(1))) void*)gb,
                    (__attribute__((address_space(3))) void*)((char*)Bs + chunk * 1024),
                    16, 0, 0);
            }
        }
        __syncthreads();
        const unsigned short* Bt = diag ? As : Bs;
        #pragma unroll
        for (int kk = 0; kk < 64; kk += 32) {
            // swizzled read col: (row&7) == (lane&7) for both A and B frags
            const int csw0 = (kk + ((lane >> 4) << 3)) ^ ((lane & 7) << 3);
            bf16x8 a[4], b[4];
            #pragma unroll
            for (int m = 0; m < 4; m++) {
                const int row = wr * 64 + m * 16 + (lane & 15);
                a[m] = *(const bf16x8*)(As + row * 64 + csw0);
            }
            #pragma unroll
            for (int n = 0; n < 4; n++) {
                const int row = wc * 64 + n * 16 + (lane & 15);
                b[n] = *(const bf16x8*)(Bt + row * 64 + csw0);
            }
            #pragma unroll
            for (int m = 0; m < 4; m++)
                #pragma unroll
                for (int n = 0; n < 4; n++)
                    acc[m][n] = __builtin_amdgcn_mfma_f32_16x16x32_bf16(
                        a[m], b[n], acc[m][n], 0, 0, 0);
        }
        __syncthreads();
    }

    // epilogue: e = exp(2*s); row-sums -> den[i-panel]; col-sums -> den[j-panel]
    float cs[4] = {0.f, 0.f, 0.f, 0.f};
    #pragma unroll
    for (int m = 0; m < 4; m++) {
        #pragma unroll
        for (int r = 0; r < 4; r++) {
            float rs = 0.f;
            #pragma unroll
            for (int n = 0; n < 4; n++) {
                const float e = __expf(INV_T * acc[m][n][r]);
                rs += e;
                cs[n] += e;
            }
            rs += __shfl_xor(rs, 1);
            rs += __shfl_xor(rs, 2);
            rs += __shfl_xor(rs, 4);
            rs += __shfl_xor(rs, 8);
            if ((lane & 15) == 0) {
                const int grow = i0 + wr * 64 + m * 16 + (lane >> 4) * 4 + r;
                atomicAdd(&den[grow], rs);
            }
        }
    }
    if (!diag) {
        #pragma unroll
        for (int n = 0; n < 4; n++) {
            float c = cs[n];
            c += __shfl_xor(c, 16);
            c += __shfl_xor(c, 32);
            if (lane < 16) {
                const int gcol = j0 + wc * 64 + n * 16 + lane;
                atomicAdd(&den[gcol], c);
            }
        }
    }
}

// ---------------- Kernel 3: positives pos[i] = dot(zb[i], zb[(i+B)%2B]) ----------------
__global__ __launch_bounds__(256) void pos_kernel(
        const unsigned short* __restrict__ zb, float* __restrict__ pos) {
    const int wave = threadIdx.x >> 6, lane = threadIdx.x & 63;
    const int i = blockIdx.x * 4 + wave;
    const int p = (i + HALFB) & (NROW - 1);
    const unsigned short* a = zb + (size_t)i * CDIM;
    const unsigned short* b = zb + (size_t)p * CDIM;
    float s = 0.f;
    #pragma unroll
    for (int it = 0; it < 2; ++it) {
        const int base = it * 512 + lane * 8;
        bf16x8 va = *(const bf16x8*)(a + base);
        bf16x8 vb = *(const bf16x8*)(b + base);
        #pragma unroll
        for (int j = 0; j < 8; ++j)
            s += bf2f((unsigned short)va[j]) * bf2f((unsigned short)vb[j]);
    }
    #pragma unroll
    for (int off = 1; off < 64; off <<= 1) s += __shfl_xor(s, off);
    if (lane == 0) pos[i] = s;
}

// ---------------- Kernel 4: final loss ----------------
__global__ __launch_bounds__(256) void loss_kernel(
        const float* __restrict__ den, const float* __restrict__ pos,
        float* __restrict__ out) {
    const float E2 = 7.3890560989306495f;  // exp(2) = diagonal term
    const int tid = threadIdx.x;
    float acc = 0.f;
    for (int i = tid; i < NROW; i += 256)
        acc += INV_T * pos[i] - logf(den[i] - E2);
    #pragma unroll
    for (int off = 1; off < 64; off <<= 1) acc += __shfl_xor(acc, off);
    __shared__ float wsum[4];
    const int lane = tid & 63, wv = tid >> 6;
    if (lane == 0) wsum[wv] = acc;
    __syncthreads();
    if (tid == 0) out[0] = -(wsum[0] + wsum[1] + wsum[2] + wsum[3]) * (1.0f / NROW);
}

extern "C" void kernel_launch(void* const* d_in, const int* in_sizes, int n_in,
                              void* d_out, int out_size, void* d_ws, size_t ws_size,
                              hipStream_t stream) {
    const float* z1 = (const float*)d_in[0];
    const float* z2 = (const float*)d_in[1];
    float* out = (float*)d_out;

    unsigned short* zb = (unsigned short*)d_ws;                      // 8 MB
    float* den = (float*)((char*)d_ws + (size_t)NROW * CDIM * 2);    // 16 KB
    float* pos = den + NROW;                                         // 16 KB

    normalize_kernel<<<NROW, 256, 0, stream>>>(z1, z2, zb);
    hipMemsetAsync(den, 0, NROW * sizeof(float), stream);
    gemm_den_kernel<<<NTRI, 256, 0, stream>>>(zb, den);
    pos_kernel<<<NROW / 4, 256, 0, stream>>>(zb, pos);
    loss_kernel<<<1, 256, 0, stream>>>(den, pos, out);
}